// Round 7
// baseline (369.625 us; speedup 1.0000x reference)
//
#include <hip/hip_runtime.h>

#define N_SAMP   1024
#define IN_F     512
#define OUT_F    512
#define N_HEADS  32
#define N_SPLITS 4
#define DELTA_SCALE 0.1f

__device__ __forceinline__ void fma4(float4& a, float x, const float4& w) {
    a.x += x * w.x; a.y += x * w.y; a.z += x * w.z; a.w += x * w.w;
}

// One grouped role pass, TILE=128 cols, thread = (ct = col-quad 0..31, kq = 0..7).
// R6 was LDS-instruction-bound: ds_read_b128 ~12cyc/CU and cols=2 gave only
// 8 FMA per read. cols=4 doubles FMA per ds_read -> LDS pipe ~10us/CU, under
// the HBM stream. W/D go HBM->registers (dist-1 double-buffer, alternating
// indices). k-partials (KQ=8) reduced via two half-col LDS phases (Red
// aliases buf, 64KB max). Sole-owner stores; DELTA writes raw partials to ws
// (combine kernel applies 0.1 and adds) so base/delta blocks can run
// concurrently in one dispatch with zero ordering constraints.
template <int J, int NSG, bool DELTA>
__device__ __forceinline__ void role_pass(
    const float* __restrict__ X, const int* __restrict__ head_ix,
    const int* __restrict__ split_ix, const float* __restrict__ Wt,
    const float* __restrict__ bias, float* __restrict__ dst,
    int g, int tileIdx, int sg, float* buf, int* list, int* wsum)
{
    constexpr int KQ  = 8;
    constexpr int KT  = IN_F / KQ;   // 64 k-rows per thread stripe
    constexpr int NST = KT / 4;      // 16 steps of 4 rows

    const int tid  = threadIdx.x;
    const int lane = tid & 63, wave = tid >> 6;
    const int ct   = tid & 31;       // col-quad within the 128-col tile
    const int kq   = tid >> 5;       // k-eighth
    const int c0   = tileIdx * 128;

    // deterministic order-preserving compaction (all blocks of group g agree)
    int run = 0;
    for (int r = 0; r < N_SAMP / 256; ++r) {
        const int i   = r * 256 + tid;
        const int key = DELTA ? head_ix[i] * N_SPLITS + split_ix[i] : head_ix[i];
        const bool hit = (key == g);
        const unsigned long long m = __ballot(hit);
        if (lane == 0) wsum[wave] = __popcll(m);
        __syncthreads();
        int base = run;
        for (int w = 0; w < 4; ++w)
            if (w < wave) base += wsum[w];
        if (hit)
            list[base + __popcll(m & ((1ULL << lane) - 1ULL))] = i;
        run += wsum[0] + wsum[1] + wsum[2] + wsum[3];
        __syncthreads();
    }
    const int total = run;
    if (total == 0 || total <= sg * J) return;   // block-uniform exit

    const float* wp = Wt + (size_t)g * (IN_F * OUT_F)
                    + (size_t)(kq * KT) * OUT_F + c0 + ct * 4;

    for (int s0 = sg * J; s0 < total; s0 += NSG * J) {
        const int nc = min(total - s0, J);

        __syncthreads();               // buf may hold previous Red
        for (int i = tid; i < J * (IN_F / 4); i += 256) {
            const int s = i >> 7, q = i & 127;
            float4 v = make_float4(0.f, 0.f, 0.f, 0.f);
            if (s < nc)
                v = *(const float4*)(X + (size_t)list[s0 + s] * IN_F + q * 4);
            *(float4*)(&buf[s * IN_F + q * 4]) = v;
        }
        __syncthreads();

        float4 acc[J];
#pragma unroll
        for (int j = 0; j < J; ++j) acc[j] = make_float4(0.f, 0.f, 0.f, 0.f);

        float4 rb[2][4];
#pragma unroll
        for (int u = 0; u < 4; ++u)
            rb[0][u] = *(const float4*)(wp + (size_t)u * OUT_F);

        const float* xb = &buf[kq * KT];
        for (int st = 0; st < NST; ++st) {
            const int nx = (st + 1 < NST) ? st + 1 : NST - 1;  // clamped tail
            const int nb = (st + 1) & 1, cb = st & 1;
            const float* wn = wp + (size_t)(nx * 4) * OUT_F;
#pragma unroll
            for (int u = 0; u < 4; ++u)
                rb[nb][u] = *(const float4*)(wn + (size_t)u * OUT_F);
#pragma unroll
            for (int j = 0; j < J; ++j) {   // wave-uniform per kq: 2-way broadcast
                const float4 xv = *(const float4*)(xb + j * IN_F + st * 4);
                fma4(acc[j], xv.x, rb[cb][0]);
                fma4(acc[j], xv.y, rb[cb][1]);
                fma4(acc[j], xv.z, rb[cb][2]);
                fma4(acc[j], xv.w, rb[cb][3]);
            }
        }

        // epilogue: KQ-reduce via LDS, one 64-col half at a time
        __syncthreads();               // Xs consumed; reuse buf as Red
        float4* Red = (float4*)buf;    // [KQ][J][16] float4 per half (<=64KB)
#pragma unroll
        for (int half = 0; half < 2; ++half) {
            if ((ct >> 4) == half) {
                const int cth = ct & 15;
#pragma unroll
                for (int j = 0; j < J; ++j)
                    Red[(kq * J + j) * 16 + cth] = acc[j];
            }
            __syncthreads();
            for (int t = tid; t < J * 16; t += 256) {
                const int j = t >> 4, cq = t & 15;
                if (j < nc) {
                    float4 s = Red[j * 16 + cq];
#pragma unroll
                    for (int q = 1; q < KQ; ++q) {
                        const float4 r = Red[(q * J + j) * 16 + cq];
                        s.x += r.x; s.y += r.y; s.z += r.z; s.w += r.w;
                    }
                    const int col = c0 + half * 64 + cq * 4;
                    float* op = dst + (size_t)list[s0 + j] * OUT_F + col;
                    if (DELTA) {
                        *(float4*)op = s;          // raw partial into ws
                    } else {
                        const float4 bv =
                            *(const float4*)(bias + (size_t)g * OUT_F + col);
                        s.x += bv.x; s.y += bv.y; s.z += bv.z; s.w += bv.w;
                        *(float4*)op = s;
                    }
                }
            }
            __syncthreads();           // before next half overwrites Red
        }
    }
}

// 768 blocks: bid%3==0 -> base (32 heads x 4 tiles x 2 sg = 256 blocks,
// writes out = acc + bias); else -> delta (128 combos x 4 tiles = 512 blocks,
// writes raw partials to ws). Disjoint destinations -> safe concurrency.
__global__ __launch_bounds__(256, 2) void lms_fused(
    const float* __restrict__ X, const int* __restrict__ head_ix,
    const int* __restrict__ split_ix, const float* __restrict__ W,
    const float* __restrict__ D, const float* __restrict__ bias,
    float* __restrict__ out, float* __restrict__ ws)
{
    __shared__ float buf[16384];       // 64 KB: Xs[J][512] <-> Red
    __shared__ int   list[N_SAMP];
    __shared__ int   wsum[4];

    const int bid = blockIdx.x;
    const int r3  = bid % 3;
    if (r3 == 0) {
        const int id = bid / 3;                 // 0..255
        const int head = id & 31;
        const int tile = (id >> 5) & 3;
        const int sg   = id >> 7;               // 0..1
        role_pass<32, 2, false>(X, head_ix, split_ix,
            W, bias, out, head, tile, sg, buf, list, wsum);
    } else {
        const int id = (bid / 3) * 2 + (r3 - 1);  // 0..511
        const int combo = id & 127;
        const int tile  = id >> 7;              // 0..3
        role_pass<16, 1, true>(X, head_ix, split_ix,
            D, bias, ws, combo, tile, 0, buf, list, wsum);
    }
}

// out += 0.1 * ws  (every (n,c) slice of ws was written: sample n's combo is
// non-empty by construction, so its 4 tile-blocks covered all 512 cols)
__global__ __launch_bounds__(256) void combine_kernel(
    float* __restrict__ out, const float* __restrict__ ws)
{
    const int i = blockIdx.x * 256 + threadIdx.x;
    float4 o = ((float4*)out)[i];
    const float4 d = ((const float4*)ws)[i];
    o.x += DELTA_SCALE * d.x; o.y += DELTA_SCALE * d.y;
    o.z += DELTA_SCALE * d.z; o.w += DELTA_SCALE * d.w;
    ((float4*)out)[i] = o;
}

extern "C" void kernel_launch(void* const* d_in, const int* in_sizes, int n_in,
                              void* d_out, int out_size, void* d_ws, size_t ws_size,
                              hipStream_t stream) {
    const float* X        = (const float*)d_in[0];
    const int*   head_ix  = (const int*)d_in[1];
    const int*   split_ix = (const int*)d_in[2];
    const float* W        = (const float*)d_in[3];
    const float* D        = (const float*)d_in[4];
    const float* bias     = (const float*)d_in[5];
    float*       out      = (float*)d_out;
    float*       ws       = (float*)d_ws;

    lms_fused<<<768, 256, 0, stream>>>(X, head_ix, split_ix, W, D, bias, out, ws);
    combine_kernel<<<(N_SAMP * OUT_F / 4) / 256, 256, 0, stream>>>(out, ws);
}